// Round 5
// baseline (170.892 us; speedup 1.0000x reference)
//
#include <hip/hip_runtime.h>

#define H 1024
#define HH (H * H)          // 1048576 per channel plane
#define CHW (3 * HH)        // 3145728 per image
#define NB 256
#define HIST_BLOCKS 512     // 2 blocks/CU exactly (R4: beat 768 by ~4us — less merge/fixed cost)
#define FIN_BLOCKS 1024     // R5: exact map, 256 thr/block, 4 blocks/CU = 16 waves/CU

#define MARK (1u << 24)     // sample-mark bit in pk_dst (bins live in bytes 0-2)
#define BINS3 0x00FFFFFFu

__device__ __forceinline__ float clamp01(float x) { return fminf(fmaxf(x, 0.0f), 1.0f); }

// bin of a value already divided by 255 (v01 = masked_value/255, mask in {0,1})
// (int)(v01*255) is bit-exact vs reference's (int)(clamp01(..)*255*mask).
__device__ __forceinline__ unsigned int bin8(float v01) {
    int b = (int)(v01 * 255.0f);
    return (unsigned int)min(max(b, 0), NB - 1);
}

// ---------------------------------------------------------------------------
// Stage 1: elementwise masking + packed per-pixel bin triples.
// Block 0 zeroes ghist[1536] + loss (kernel-boundary ordering gives k_hist
// visibility). No bitmap anymore (R5: mark bit lives in pk_dst byte 3).
// [R3 post-mortem: count-based hist regressed +7us — pk is L3-hot for
//  k_hist, random gathers are cheap; keep the gather structure.]
// ---------------------------------------------------------------------------
__global__ void k_elementwise(const float4* __restrict__ inp,
                              const float4* __restrict__ tar,
                              const float4* __restrict__ rfp,
                              const float4* __restrict__ msrc,
                              const float4* __restrict__ mtar,
                              float4* __restrict__ out0, float4* __restrict__ out1,
                              float4* __restrict__ out2,
                              uint4* __restrict__ pk_dst, uint4* __restrict__ pk_ref,
                              unsigned int* __restrict__ gz,
                              float* __restrict__ loss)
{
    if (blockIdx.x == 0) {
        for (int i = threadIdx.x; i < 1536; i += blockDim.x) gz[i] = 0u;  // ghist
        if (threadIdx.x == 0) *loss = 0.0f;
    }
    int p = blockIdx.x * blockDim.x + threadIdx.x;
    if (p >= HH / 4) return;
    float4 ms4 = msrc[p], mt4 = mtar[p];
    // true division: 255.0f/255.0f == 1.0f exactly
    float msx = ms4.x / 255.0f, msy = ms4.y / 255.0f, msz = ms4.z / 255.0f, msw = ms4.w / 255.0f;
    float mtx = mt4.x / 255.0f, mty = mt4.y / 255.0f, mtz = mt4.z / 255.0f, mtw = mt4.w / 255.0f;
    unsigned int bd0 = 0, bd1 = 0, bd2 = 0, bd3 = 0;
    unsigned int br0 = 0, br1 = 0, br2 = 0, br3 = 0;
#pragma unroll
    for (int c = 0; c < 3; ++c) {
        int q = c * (HH / 4) + p;
        float4 t = tar[q], r = rfp[q], iv = inp[q];
        float4 o0, o1, o2;
        o0.x = clamp01((t.x + 1.0f) * 0.5f) * mtx;
        o0.y = clamp01((t.y + 1.0f) * 0.5f) * mty;
        o0.z = clamp01((t.z + 1.0f) * 0.5f) * mtz;
        o0.w = clamp01((t.w + 1.0f) * 0.5f) * mtw;
        o1.x = clamp01((r.x + 1.0f) * 0.5f) * msx;
        o1.y = clamp01((r.y + 1.0f) * 0.5f) * msy;
        o1.z = clamp01((r.z + 1.0f) * 0.5f) * msz;
        o1.w = clamp01((r.w + 1.0f) * 0.5f) * msw;
        o2.x = clamp01(iv.x) * msx;
        o2.y = clamp01(iv.y) * msy;
        o2.z = clamp01(iv.z) * msz;
        o2.w = clamp01(iv.w) * msw;
        out0[q] = o0;
        out1[q] = o1;
        out2[q] = o2;
        int sh = 8 * c;
        bd0 |= bin8(o1.x) << sh;  bd1 |= bin8(o1.y) << sh;
        bd2 |= bin8(o1.z) << sh;  bd3 |= bin8(o1.w) << sh;
        br0 |= bin8(o0.x) << sh;  br1 |= bin8(o0.y) << sh;
        br2 |= bin8(o0.z) << sh;  br3 |= bin8(o0.w) << sh;
    }
    pk_dst[p] = make_uint4(bd0, bd1, bd2, bd3);
    pk_ref[p] = make_uint4(br0, br1, br2, br3);
}

// ---------------------------------------------------------------------------
// Stage 2: histograms from packed bins. R5: the dst gather and the sample
// mark are ONE op — atomicOr(&pk_dst[pd], MARK) returns the old value (the
// bins) while setting bit 24. Removes 400K separate bitmap atomics from this
// latency-bound kernel. Zero-ballot test masks the (possibly already-set)
// mark bit, so count semantics are identical to the verified R4 version.
// pk arrays are L3-hot (written by stage 1); gathers hidden by 262K threads.
// ---------------------------------------------------------------------------
__global__ void k_hist(unsigned int* __restrict__ pk_dst,
                       const unsigned int* __restrict__ pk_ref,
                       const int* __restrict__ i0, const int* __restrict__ i1,
                       const int* __restrict__ i2, const int* __restrict__ i3,
                       unsigned int* __restrict__ ghist, int n)
{
    __shared__ unsigned int h[2 * 3 * NB];
    for (int i = threadIdx.x; i < 2 * 3 * NB; i += blockDim.x) h[i] = 0u;
    __syncthreads();

    int lane = threadIdx.x & 63;
    for (int k = blockIdx.x * blockDim.x + threadIdx.x; k < n; k += gridDim.x * blockDim.x) {
        int pd = i0[k] * H + i1[k];
        int pr = i2[k] * H + i3[k];
        unsigned int a = atomicOr(&pk_dst[pd], MARK) & BINS3;   // gather + mark in one RMW
        unsigned int b = pk_ref[pr];

        unsigned long long mza = __ballot(a == 0u);
        if (a != 0u) {
            atomicAdd(&h[        (a       & 255u)], 1u);
            atomicAdd(&h[  NB + ((a >> 8) & 255u)], 1u);
            atomicAdd(&h[2*NB + ((a >>16) & 255u)], 1u);
        } else if (lane == __ffsll(mza) - 1) {
            unsigned int cnt = (unsigned int)__popcll(mza);
            atomicAdd(&h[0],      cnt);
            atomicAdd(&h[NB],     cnt);
            atomicAdd(&h[2 * NB], cnt);
        }

        unsigned long long mzb = __ballot(b == 0u);
        if (b != 0u) {
            atomicAdd(&h[3*NB + ( b       & 255u)], 1u);
            atomicAdd(&h[4*NB + ((b >> 8) & 255u)], 1u);
            atomicAdd(&h[5*NB + ((b >>16) & 255u)], 1u);
        } else if (lane == __ffsll(mzb) - 1) {
            unsigned int cnt = (unsigned int)__popcll(mzb);
            atomicAdd(&h[3 * NB], cnt);
            atomicAdd(&h[4 * NB], cnt);
            atomicAdd(&h[5 * NB], cnt);
        }
    }
    __syncthreads();
    for (int i = threadIdx.x; i < 2 * 3 * NB; i += blockDim.x) {
        unsigned int v = h[i];
        if (v) atomicAdd(&ghist[i], v);
    }
}

// ---------------------------------------------------------------------------
// Stage 3 (fused tables + out3 + loss). Every block redundantly computes the
// cdf/transfer table from ghist (6KB L2-hot; identical float compares to the
// verified path), then streams out3 densely, one 4-pixel group per thread:
//   out3 = (pk bit24) ? table[pk byte c] : out1
// Stored bins are bit-identical to recomputing bin8(out1) (same producer).
// Loss fused in the same pass. 256 thr x 1024 blocks = 16 waves/CU.
// ---------------------------------------------------------------------------
__global__ __launch_bounds__(256)
void k_finalize(const uint4* __restrict__ ghist4,
                const uint4* __restrict__ pkv,
                const float4* __restrict__ out1v,
                const float4* __restrict__ out2v,
                float4* __restrict__ out3v,
                float* __restrict__ loss)
{
    __shared__ float cdf[6][NB];     // rows 0-2: cdf_dst, rows 3-5: cdf_ref
    __shared__ float tl[3 * NB];     // tables, PRE-DIVIDED by 255
    __shared__ float ws[4];
    int t = threadIdx.x;
    int wave = t >> 6, lane = t & 63;

    // --- per-block table compute (4 waves; waves 0,1 take two rows) ---
    for (int row = wave; row < 6; row += 4) {
        uint4 v = ghist4[row * 64 + lane];
        unsigned int s0 = v.x;
        unsigned int s1 = s0 + v.y;
        unsigned int s2 = s1 + v.z;
        unsigned int s3 = s2 + v.w;
        unsigned int scan = s3;
#pragma unroll
        for (int off = 1; off < 64; off <<= 1) {
            unsigned int u = (unsigned int)__shfl_up((int)scan, off, 64);
            if (lane >= off) scan += u;
        }
        unsigned int prefix = scan - s3;
        float ft = (float)(unsigned int)__shfl((int)scan, 63, 64);
        cdf[row][lane * 4 + 0] = (float)(prefix + s0) / ft;
        cdf[row][lane * 4 + 1] = (float)(prefix + s1) / ft;
        cdf[row][lane * 4 + 2] = (float)(prefix + s2) / ft;
        cdf[row][lane * 4 + 3] = (float)(prefix + s3) / ft;
    }
    __syncthreads();

    {   // t in [0,256): every thread searches one cdf row entry per channel
#pragma unroll
        for (int c = 0; c < 3; ++c) {
            float r = cdf[c][t];
            const float* cr = cdf[3 + c];
            int lo = 1, hi = NB - 1;
#pragma unroll
            for (int it = 0; it < 8; ++it) {
                int mid = (lo + hi) >> 1;
                if (cr[mid] >= r) hi = mid; else lo = mid + 1;
            }
            int jstar = lo - 1;
            int tab = (jstar == 0 && cr[0] > r) ? t : (jstar + 1);
            if (t == NB - 1) tab = NB - 1;
            tl[c * NB + t] = (float)tab / 255.0f;
        }
    }
    __syncthreads();

    // --- dense out3 + loss streaming pass (exactly one 4-pixel group/thread) ---
    const int n4 = HH / 4;
    const int k = blockIdx.x * 256 + t;
    uint4 pk = pkv[k];                       // bins bytes 0-2, mark bit 24
    float s = 0.0f;
#pragma unroll
    for (int c = 0; c < 3; ++c) {
        const float* tc = &tl[c * NB];
        int sh = 8 * c;
        float4 a = out1v[c * n4 + k];
        float4 b = out2v[c * n4 + k];
        float4 o;
        o.x = (pk.x & MARK) ? tc[(pk.x >> sh) & 255u] : a.x;
        o.y = (pk.y & MARK) ? tc[(pk.y >> sh) & 255u] : a.y;
        o.z = (pk.z & MARK) ? tc[(pk.z >> sh) & 255u] : a.z;
        o.w = (pk.w & MARK) ? tc[(pk.w >> sh) & 255u] : a.w;
        out3v[c * n4 + k] = o;
        s += fabsf(b.x - o.x) + fabsf(b.y - o.y) + fabsf(b.z - o.z) + fabsf(b.w - o.w);
    }
#pragma unroll
    for (int off = 32; off > 0; off >>= 1) s += __shfl_down(s, off);
    if (lane == 0) ws[wave] = s;
    __syncthreads();
    if (t == 0) {
        float tsum = ws[0] + ws[1] + ws[2] + ws[3];
        atomicAdd(loss, tsum * (1.0f / (float)CHW));
    }
}

extern "C" void kernel_launch(void* const* d_in, const int* in_sizes, int n_in,
                              void* d_out, int out_size, void* d_ws, size_t ws_size,
                              hipStream_t stream)
{
    const float* inp  = (const float*)d_in[0];
    const float* tar  = (const float*)d_in[1];
    const float* rfp  = (const float*)d_in[2];
    const float* msrc = (const float*)d_in[3];
    const float* mtar = (const float*)d_in[4];
    // d_in[5] = target_data_eye (unused by the reference computation)
    const int* i0 = (const int*)d_in[6];
    const int* i1 = (const int*)d_in[7];
    const int* i2 = (const int*)d_in[8];
    const int* i3 = (const int*)d_in[9];
    int n = in_sizes[6];

    float* out0 = (float*)d_out;
    float* out1 = out0 + CHW;
    float* out2 = out1 + CHW;
    float* out3 = out2 + CHW;
    float* loss = out3 + CHW;

    // workspace layout
    unsigned int* ghist  = (unsigned int*)d_ws;                      // [0, 6144): 1536 u32
    unsigned int* pk_dst = (unsigned int*)((char*)d_ws + 8192);      // HH u32 (4 MB)
    unsigned int* pk_ref = pk_dst + HH;                              // HH u32 (4 MB)

    k_elementwise<<<(HH / 4 + 255) / 256, 256, 0, stream>>>(
        (const float4*)inp, (const float4*)tar, (const float4*)rfp,
        (const float4*)msrc, (const float4*)mtar,
        (float4*)out0, (float4*)out1, (float4*)out2,
        (uint4*)pk_dst, (uint4*)pk_ref, ghist, loss);

    k_hist<<<HIST_BLOCKS, 512, 0, stream>>>(pk_dst, pk_ref, i0, i1, i2, i3, ghist, n);

    k_finalize<<<FIN_BLOCKS, 256, 0, stream>>>(
        (const uint4*)ghist, (const uint4*)pk_dst,
        (const float4*)out1, (const float4*)out2, (float4*)out3, loss);
}

// Round 6
// 167.930 us; speedup vs baseline: 1.0176x; 1.0176x over previous
//
#include <hip/hip_runtime.h>

#define H 1024
#define HH (H * H)          // 1048576 per channel plane
#define CHW (3 * HH)        // 3145728 per image
#define NB 256
#define HIST_BLOCKS 512     // 256 dst-side + 256 ref-side blocks (R6 split)
#define FIN_BLOCKS 1024     // exact map, 256 thr/block, 4 blocks/CU = 16 waves/CU

#define MARK (1u << 24)     // sample-mark bit in pk_dst (bins live in bytes 0-2)
#define BINS3 0x00FFFFFFu

__device__ __forceinline__ float clamp01(float x) { return fminf(fmaxf(x, 0.0f), 1.0f); }

// bin of a value already divided by 255 (v01 = masked_value/255, mask in {0,1})
// (int)(v01*255) is bit-exact vs reference's (int)(clamp01(..)*255*mask).
__device__ __forceinline__ unsigned int bin8(float v01) {
    int b = (int)(v01 * 255.0f);
    return (unsigned int)min(max(b, 0), NB - 1);
}

// ---------------------------------------------------------------------------
// Stage 1: elementwise masking + packed per-pixel bin triples.
// Block 0 zeroes ghist[1536] + loss (kernel-boundary ordering gives k_hist
// visibility). Mark bit lives in pk_dst byte 3 (R5).
// [R3 post-mortem: count-based hist regressed +7us — pk is L3-hot for
//  k_hist, random gathers are cheap; keep the gather structure.]
// ---------------------------------------------------------------------------
__global__ void k_elementwise(const float4* __restrict__ inp,
                              const float4* __restrict__ tar,
                              const float4* __restrict__ rfp,
                              const float4* __restrict__ msrc,
                              const float4* __restrict__ mtar,
                              float4* __restrict__ out0, float4* __restrict__ out1,
                              float4* __restrict__ out2,
                              uint4* __restrict__ pk_dst, uint4* __restrict__ pk_ref,
                              unsigned int* __restrict__ gz,
                              float* __restrict__ loss)
{
    if (blockIdx.x == 0) {
        for (int i = threadIdx.x; i < 1536; i += blockDim.x) gz[i] = 0u;  // ghist
        if (threadIdx.x == 0) *loss = 0.0f;
    }
    int p = blockIdx.x * blockDim.x + threadIdx.x;   // grid exact: 1024*256 == HH/4
    float4 ms4 = msrc[p], mt4 = mtar[p];
    // true division: 255.0f/255.0f == 1.0f exactly
    float msx = ms4.x / 255.0f, msy = ms4.y / 255.0f, msz = ms4.z / 255.0f, msw = ms4.w / 255.0f;
    float mtx = mt4.x / 255.0f, mty = mt4.y / 255.0f, mtz = mt4.z / 255.0f, mtw = mt4.w / 255.0f;
    unsigned int bd0 = 0, bd1 = 0, bd2 = 0, bd3 = 0;
    unsigned int br0 = 0, br1 = 0, br2 = 0, br3 = 0;
#pragma unroll
    for (int c = 0; c < 3; ++c) {
        int q = c * (HH / 4) + p;
        float4 t = tar[q], r = rfp[q], iv = inp[q];
        float4 o0, o1, o2;
        o0.x = clamp01((t.x + 1.0f) * 0.5f) * mtx;
        o0.y = clamp01((t.y + 1.0f) * 0.5f) * mty;
        o0.z = clamp01((t.z + 1.0f) * 0.5f) * mtz;
        o0.w = clamp01((t.w + 1.0f) * 0.5f) * mtw;
        o1.x = clamp01((r.x + 1.0f) * 0.5f) * msx;
        o1.y = clamp01((r.y + 1.0f) * 0.5f) * msy;
        o1.z = clamp01((r.z + 1.0f) * 0.5f) * msz;
        o1.w = clamp01((r.w + 1.0f) * 0.5f) * msw;
        o2.x = clamp01(iv.x) * msx;
        o2.y = clamp01(iv.y) * msy;
        o2.z = clamp01(iv.z) * msz;
        o2.w = clamp01(iv.w) * msw;
        out0[q] = o0;
        out1[q] = o1;
        out2[q] = o2;
        int sh = 8 * c;
        bd0 |= bin8(o1.x) << sh;  bd1 |= bin8(o1.y) << sh;
        bd2 |= bin8(o1.z) << sh;  bd3 |= bin8(o1.w) << sh;
        br0 |= bin8(o0.x) << sh;  br1 |= bin8(o0.y) << sh;
        br2 |= bin8(o0.z) << sh;  br3 |= bin8(o0.w) << sh;
    }
    pk_dst[p] = make_uint4(bd0, bd1, bd2, bd3);
    pk_ref[p] = make_uint4(br0, br1, br2, br3);
}

// ---------------------------------------------------------------------------
// Stage 2 (R6: side-split): blocks [0,256) process dst samples only, blocks
// [256,512) ref samples only. Same 800K total gathers and same thread count
// as the R4/R5 combined version, but: ghist merge atomics halved
// (512x1536 -> 512x768 — the same term that made 768->512 blocks a win in
// R4), LDS zero halved, one gather + one ballot per loop iteration.
// dst gather+mark stays one RMW (atomicOr returns old value = bins).
// pk arrays are L3-hot (written by stage 1).
// ---------------------------------------------------------------------------
__global__ void k_hist(unsigned int* __restrict__ pk_dst,
                       const unsigned int* __restrict__ pk_ref,
                       const int* __restrict__ i0, const int* __restrict__ i1,
                       const int* __restrict__ i2, const int* __restrict__ i3,
                       unsigned int* __restrict__ ghist, int n)
{
    __shared__ unsigned int h[3 * NB];
    for (int i = threadIdx.x; i < 3 * NB; i += blockDim.x) h[i] = 0u;
    __syncthreads();

    const int lane = threadIdx.x & 63;
    const int half = HIST_BLOCKS / 2;                 // 256
    const bool dst_side = blockIdx.x < half;
    const int bid = dst_side ? blockIdx.x : blockIdx.x - half;
    const int stride = half * blockDim.x;             // 131072

    if (dst_side) {
        for (int k = bid * blockDim.x + threadIdx.x; k < n; k += stride) {
            int pd = i0[k] * H + i1[k];
            unsigned int a = atomicOr(&pk_dst[pd], MARK) & BINS3;  // gather + mark in one RMW
            unsigned long long mz = __ballot(a == 0u);
            if (a != 0u) {
                atomicAdd(&h[        (a       & 255u)], 1u);
                atomicAdd(&h[  NB + ((a >> 8) & 255u)], 1u);
                atomicAdd(&h[2*NB + ((a >>16) & 255u)], 1u);
            } else if (lane == __ffsll(mz) - 1) {
                unsigned int cnt = (unsigned int)__popcll(mz);
                atomicAdd(&h[0],      cnt);
                atomicAdd(&h[NB],     cnt);
                atomicAdd(&h[2 * NB], cnt);
            }
        }
    } else {
        for (int k = bid * blockDim.x + threadIdx.x; k < n; k += stride) {
            int pr = i2[k] * H + i3[k];
            unsigned int b = pk_ref[pr];
            unsigned long long mz = __ballot(b == 0u);
            if (b != 0u) {
                atomicAdd(&h[        (b       & 255u)], 1u);
                atomicAdd(&h[  NB + ((b >> 8) & 255u)], 1u);
                atomicAdd(&h[2*NB + ((b >>16) & 255u)], 1u);
            } else if (lane == __ffsll(mz) - 1) {
                unsigned int cnt = (unsigned int)__popcll(mz);
                atomicAdd(&h[0],      cnt);
                atomicAdd(&h[NB],     cnt);
                atomicAdd(&h[2 * NB], cnt);
            }
        }
    }
    __syncthreads();
    unsigned int* gbase = ghist + (dst_side ? 0 : 3 * NB);
    for (int i = threadIdx.x; i < 3 * NB; i += blockDim.x) {
        unsigned int v = h[i];
        if (v) atomicAdd(&gbase[i], v);
    }
}

// ---------------------------------------------------------------------------
// Stage 3 (fused tables + out3 + loss). Every block redundantly computes the
// cdf/transfer table from ghist (6KB L2-hot; identical float compares to the
// verified path), then streams out3 densely, one 4-pixel group per thread:
//   out3 = (pk bit24) ? table[pk byte c] : out1
// Stored bins are bit-identical to recomputing bin8(out1) (same producer).
// Loss fused in the same pass.
// ---------------------------------------------------------------------------
__global__ __launch_bounds__(256)
void k_finalize(const uint4* __restrict__ ghist4,
                const uint4* __restrict__ pkv,
                const float4* __restrict__ out1v,
                const float4* __restrict__ out2v,
                float4* __restrict__ out3v,
                float* __restrict__ loss)
{
    __shared__ float cdf[6][NB];     // rows 0-2: cdf_dst, rows 3-5: cdf_ref
    __shared__ float tl[3 * NB];     // tables, PRE-DIVIDED by 255
    __shared__ float ws[4];
    int t = threadIdx.x;
    int wave = t >> 6, lane = t & 63;

    // --- per-block table compute (4 waves; waves 0,1 take two rows) ---
    for (int row = wave; row < 6; row += 4) {
        uint4 v = ghist4[row * 64 + lane];
        unsigned int s0 = v.x;
        unsigned int s1 = s0 + v.y;
        unsigned int s2 = s1 + v.z;
        unsigned int s3 = s2 + v.w;
        unsigned int scan = s3;
#pragma unroll
        for (int off = 1; off < 64; off <<= 1) {
            unsigned int u = (unsigned int)__shfl_up((int)scan, off, 64);
            if (lane >= off) scan += u;
        }
        unsigned int prefix = scan - s3;
        float ft = (float)(unsigned int)__shfl((int)scan, 63, 64);
        cdf[row][lane * 4 + 0] = (float)(prefix + s0) / ft;
        cdf[row][lane * 4 + 1] = (float)(prefix + s1) / ft;
        cdf[row][lane * 4 + 2] = (float)(prefix + s2) / ft;
        cdf[row][lane * 4 + 3] = (float)(prefix + s3) / ft;
    }
    __syncthreads();

    {   // t in [0,256): every thread searches one cdf row entry per channel
#pragma unroll
        for (int c = 0; c < 3; ++c) {
            float r = cdf[c][t];
            const float* cr = cdf[3 + c];
            int lo = 1, hi = NB - 1;
#pragma unroll
            for (int it = 0; it < 8; ++it) {
                int mid = (lo + hi) >> 1;
                if (cr[mid] >= r) hi = mid; else lo = mid + 1;
            }
            int jstar = lo - 1;
            int tab = (jstar == 0 && cr[0] > r) ? t : (jstar + 1);
            if (t == NB - 1) tab = NB - 1;
            tl[c * NB + t] = (float)tab / 255.0f;
        }
    }
    __syncthreads();

    // --- dense out3 + loss streaming pass (exactly one 4-pixel group/thread) ---
    const int n4 = HH / 4;
    const int k = blockIdx.x * 256 + t;
    uint4 pk = pkv[k];                       // bins bytes 0-2, mark bit 24
    float s = 0.0f;
#pragma unroll
    for (int c = 0; c < 3; ++c) {
        const float* tc = &tl[c * NB];
        int sh = 8 * c;
        float4 a = out1v[c * n4 + k];
        float4 b = out2v[c * n4 + k];
        float4 o;
        o.x = (pk.x & MARK) ? tc[(pk.x >> sh) & 255u] : a.x;
        o.y = (pk.y & MARK) ? tc[(pk.y >> sh) & 255u] : a.y;
        o.z = (pk.z & MARK) ? tc[(pk.z >> sh) & 255u] : a.z;
        o.w = (pk.w & MARK) ? tc[(pk.w >> sh) & 255u] : a.w;
        out3v[c * n4 + k] = o;
        s += fabsf(b.x - o.x) + fabsf(b.y - o.y) + fabsf(b.z - o.z) + fabsf(b.w - o.w);
    }
#pragma unroll
    for (int off = 32; off > 0; off >>= 1) s += __shfl_down(s, off);
    if (lane == 0) ws[wave] = s;
    __syncthreads();
    if (t == 0) {
        float tsum = ws[0] + ws[1] + ws[2] + ws[3];
        atomicAdd(loss, tsum * (1.0f / (float)CHW));
    }
}

extern "C" void kernel_launch(void* const* d_in, const int* in_sizes, int n_in,
                              void* d_out, int out_size, void* d_ws, size_t ws_size,
                              hipStream_t stream)
{
    const float* inp  = (const float*)d_in[0];
    const float* tar  = (const float*)d_in[1];
    const float* rfp  = (const float*)d_in[2];
    const float* msrc = (const float*)d_in[3];
    const float* mtar = (const float*)d_in[4];
    // d_in[5] = target_data_eye (unused by the reference computation)
    const int* i0 = (const int*)d_in[6];
    const int* i1 = (const int*)d_in[7];
    const int* i2 = (const int*)d_in[8];
    const int* i3 = (const int*)d_in[9];
    int n = in_sizes[6];

    float* out0 = (float*)d_out;
    float* out1 = out0 + CHW;
    float* out2 = out1 + CHW;
    float* out3 = out2 + CHW;
    float* loss = out3 + CHW;

    // workspace layout
    unsigned int* ghist  = (unsigned int*)d_ws;                      // [0, 6144): 1536 u32
    unsigned int* pk_dst = (unsigned int*)((char*)d_ws + 8192);      // HH u32 (4 MB)
    unsigned int* pk_ref = pk_dst + HH;                              // HH u32 (4 MB)

    k_elementwise<<<HH / 4 / 256, 256, 0, stream>>>(
        (const float4*)inp, (const float4*)tar, (const float4*)rfp,
        (const float4*)msrc, (const float4*)mtar,
        (float4*)out0, (float4*)out1, (float4*)out2,
        (uint4*)pk_dst, (uint4*)pk_ref, ghist, loss);

    k_hist<<<HIST_BLOCKS, 512, 0, stream>>>(pk_dst, pk_ref, i0, i1, i2, i3, ghist, n);

    k_finalize<<<FIN_BLOCKS, 256, 0, stream>>>(
        (const uint4*)ghist, (const uint4*)pk_dst,
        (const float4*)out1, (const float4*)out2, (float4*)out3, loss);
}

// Round 7
// 166.179 us; speedup vs baseline: 1.0284x; 1.0105x over previous
//
#include <hip/hip_runtime.h>

#define H 1024
#define HH (H * H)          // 1048576 per channel plane
#define CHW (3 * HH)        // 3145728 per image
#define NB 256
#define HIST_BLOCKS 512     // 256 dst-side + 256 ref-side blocks (R6 split)
#define HIST_THREADS 1024   // R7: 2 blocks/CU x 16 waves = 32 waves/CU (was 16) — double the
                            // latency-hiding TLP for the gather chain; per-block sample count,
                            // LDS contention, and the 512x768 ghist merge term are unchanged.
#define FIN_BLOCKS 1024     // exact map, 256 thr/block, 4 blocks/CU = 16 waves/CU

#define MARK (1u << 24)     // sample-mark bit in pk_dst (bins live in bytes 0-2)
#define BINS3 0x00FFFFFFu

__device__ __forceinline__ float clamp01(float x) { return fminf(fmaxf(x, 0.0f), 1.0f); }

// bin of a value already divided by 255 (v01 = masked_value/255, mask in {0,1})
// (int)(v01*255) is bit-exact vs reference's (int)(clamp01(..)*255*mask).
__device__ __forceinline__ unsigned int bin8(float v01) {
    int b = (int)(v01 * 255.0f);
    return (unsigned int)min(max(b, 0), NB - 1);
}

// ---------------------------------------------------------------------------
// Stage 1: elementwise masking + packed per-pixel bin triples.
// Block 0 zeroes ghist[1536] + loss (kernel-boundary ordering gives k_hist
// visibility). Mark bit lives in pk_dst byte 3 (R5).
// [R3 post-mortem: count-based hist regressed +7us — pk is L3-hot for
//  k_hist, random gathers are cheap; keep the gather structure.]
// ---------------------------------------------------------------------------
__global__ void k_elementwise(const float4* __restrict__ inp,
                              const float4* __restrict__ tar,
                              const float4* __restrict__ rfp,
                              const float4* __restrict__ msrc,
                              const float4* __restrict__ mtar,
                              float4* __restrict__ out0, float4* __restrict__ out1,
                              float4* __restrict__ out2,
                              uint4* __restrict__ pk_dst, uint4* __restrict__ pk_ref,
                              unsigned int* __restrict__ gz,
                              float* __restrict__ loss)
{
    if (blockIdx.x == 0) {
        for (int i = threadIdx.x; i < 1536; i += blockDim.x) gz[i] = 0u;  // ghist
        if (threadIdx.x == 0) *loss = 0.0f;
    }
    int p = blockIdx.x * blockDim.x + threadIdx.x;   // grid exact: 1024*256 == HH/4
    float4 ms4 = msrc[p], mt4 = mtar[p];
    // true division: 255.0f/255.0f == 1.0f exactly
    float msx = ms4.x / 255.0f, msy = ms4.y / 255.0f, msz = ms4.z / 255.0f, msw = ms4.w / 255.0f;
    float mtx = mt4.x / 255.0f, mty = mt4.y / 255.0f, mtz = mt4.z / 255.0f, mtw = mt4.w / 255.0f;
    unsigned int bd0 = 0, bd1 = 0, bd2 = 0, bd3 = 0;
    unsigned int br0 = 0, br1 = 0, br2 = 0, br3 = 0;
#pragma unroll
    for (int c = 0; c < 3; ++c) {
        int q = c * (HH / 4) + p;
        float4 t = tar[q], r = rfp[q], iv = inp[q];
        float4 o0, o1, o2;
        o0.x = clamp01((t.x + 1.0f) * 0.5f) * mtx;
        o0.y = clamp01((t.y + 1.0f) * 0.5f) * mty;
        o0.z = clamp01((t.z + 1.0f) * 0.5f) * mtz;
        o0.w = clamp01((t.w + 1.0f) * 0.5f) * mtw;
        o1.x = clamp01((r.x + 1.0f) * 0.5f) * msx;
        o1.y = clamp01((r.y + 1.0f) * 0.5f) * msy;
        o1.z = clamp01((r.z + 1.0f) * 0.5f) * msz;
        o1.w = clamp01((r.w + 1.0f) * 0.5f) * msw;
        o2.x = clamp01(iv.x) * msx;
        o2.y = clamp01(iv.y) * msy;
        o2.z = clamp01(iv.z) * msz;
        o2.w = clamp01(iv.w) * msw;
        out0[q] = o0;
        out1[q] = o1;
        out2[q] = o2;
        int sh = 8 * c;
        bd0 |= bin8(o1.x) << sh;  bd1 |= bin8(o1.y) << sh;
        bd2 |= bin8(o1.z) << sh;  bd3 |= bin8(o1.w) << sh;
        br0 |= bin8(o0.x) << sh;  br1 |= bin8(o0.y) << sh;
        br2 |= bin8(o0.z) << sh;  br3 |= bin8(o0.w) << sh;
    }
    pk_dst[p] = make_uint4(bd0, bd1, bd2, bd3);
    pk_ref[p] = make_uint4(br0, br1, br2, br3);
}

// ---------------------------------------------------------------------------
// Stage 2 (side-split, R6): blocks [0,256) process dst samples only, blocks
// [256,512) ref samples only — halves the ghist merge atomics and LDS zero
// vs the combined version (the R4-proven lever). dst gather+mark stays one
// RMW (atomicOr returns old value = bins). pk arrays are L3-hot.
// R7: 1024 threads/block — gather chain is latency-bound; 32 waves/CU.
// ---------------------------------------------------------------------------
__global__ void k_hist(unsigned int* __restrict__ pk_dst,
                       const unsigned int* __restrict__ pk_ref,
                       const int* __restrict__ i0, const int* __restrict__ i1,
                       const int* __restrict__ i2, const int* __restrict__ i3,
                       unsigned int* __restrict__ ghist, int n)
{
    __shared__ unsigned int h[3 * NB];
    for (int i = threadIdx.x; i < 3 * NB; i += blockDim.x) h[i] = 0u;
    __syncthreads();

    const int lane = threadIdx.x & 63;
    const int half = HIST_BLOCKS / 2;                 // 256
    const bool dst_side = blockIdx.x < half;
    const int bid = dst_side ? blockIdx.x : blockIdx.x - half;
    const int stride = half * blockDim.x;             // 262144

    if (dst_side) {
        for (int k = bid * blockDim.x + threadIdx.x; k < n; k += stride) {
            int pd = i0[k] * H + i1[k];
            unsigned int a = atomicOr(&pk_dst[pd], MARK) & BINS3;  // gather + mark in one RMW
            unsigned long long mz = __ballot(a == 0u);
            if (a != 0u) {
                atomicAdd(&h[        (a       & 255u)], 1u);
                atomicAdd(&h[  NB + ((a >> 8) & 255u)], 1u);
                atomicAdd(&h[2*NB + ((a >>16) & 255u)], 1u);
            } else if (lane == __ffsll(mz) - 1) {
                unsigned int cnt = (unsigned int)__popcll(mz);
                atomicAdd(&h[0],      cnt);
                atomicAdd(&h[NB],     cnt);
                atomicAdd(&h[2 * NB], cnt);
            }
        }
    } else {
        for (int k = bid * blockDim.x + threadIdx.x; k < n; k += stride) {
            int pr = i2[k] * H + i3[k];
            unsigned int b = pk_ref[pr];
            unsigned long long mz = __ballot(b == 0u);
            if (b != 0u) {
                atomicAdd(&h[        (b       & 255u)], 1u);
                atomicAdd(&h[  NB + ((b >> 8) & 255u)], 1u);
                atomicAdd(&h[2*NB + ((b >>16) & 255u)], 1u);
            } else if (lane == __ffsll(mz) - 1) {
                unsigned int cnt = (unsigned int)__popcll(mz);
                atomicAdd(&h[0],      cnt);
                atomicAdd(&h[NB],     cnt);
                atomicAdd(&h[2 * NB], cnt);
            }
        }
    }
    __syncthreads();
    unsigned int* gbase = ghist + (dst_side ? 0 : 3 * NB);
    for (int i = threadIdx.x; i < 3 * NB; i += blockDim.x) {
        unsigned int v = h[i];
        if (v) atomicAdd(&gbase[i], v);
    }
}

// ---------------------------------------------------------------------------
// Stage 3 (fused tables + out3 + loss). Every block redundantly computes the
// cdf/transfer table from ghist (6KB L2-hot; identical float compares to the
// verified path), then streams out3 densely, one 4-pixel group per thread:
//   out3 = (pk bit24) ? table[pk byte c] : out1
// Stored bins are bit-identical to recomputing bin8(out1) (same producer).
// Loss fused in the same pass.
// ---------------------------------------------------------------------------
__global__ __launch_bounds__(256)
void k_finalize(const uint4* __restrict__ ghist4,
                const uint4* __restrict__ pkv,
                const float4* __restrict__ out1v,
                const float4* __restrict__ out2v,
                float4* __restrict__ out3v,
                float* __restrict__ loss)
{
    __shared__ float cdf[6][NB];     // rows 0-2: cdf_dst, rows 3-5: cdf_ref
    __shared__ float tl[3 * NB];     // tables, PRE-DIVIDED by 255
    __shared__ float ws[4];
    int t = threadIdx.x;
    int wave = t >> 6, lane = t & 63;

    // --- per-block table compute (4 waves; waves 0,1 take two rows) ---
    for (int row = wave; row < 6; row += 4) {
        uint4 v = ghist4[row * 64 + lane];
        unsigned int s0 = v.x;
        unsigned int s1 = s0 + v.y;
        unsigned int s2 = s1 + v.z;
        unsigned int s3 = s2 + v.w;
        unsigned int scan = s3;
#pragma unroll
        for (int off = 1; off < 64; off <<= 1) {
            unsigned int u = (unsigned int)__shfl_up((int)scan, off, 64);
            if (lane >= off) scan += u;
        }
        unsigned int prefix = scan - s3;
        float ft = (float)(unsigned int)__shfl((int)scan, 63, 64);
        cdf[row][lane * 4 + 0] = (float)(prefix + s0) / ft;
        cdf[row][lane * 4 + 1] = (float)(prefix + s1) / ft;
        cdf[row][lane * 4 + 2] = (float)(prefix + s2) / ft;
        cdf[row][lane * 4 + 3] = (float)(prefix + s3) / ft;
    }
    __syncthreads();

    {   // t in [0,256): every thread searches one cdf row entry per channel
#pragma unroll
        for (int c = 0; c < 3; ++c) {
            float r = cdf[c][t];
            const float* cr = cdf[3 + c];
            int lo = 1, hi = NB - 1;
#pragma unroll
            for (int it = 0; it < 8; ++it) {
                int mid = (lo + hi) >> 1;
                if (cr[mid] >= r) hi = mid; else lo = mid + 1;
            }
            int jstar = lo - 1;
            int tab = (jstar == 0 && cr[0] > r) ? t : (jstar + 1);
            if (t == NB - 1) tab = NB - 1;
            tl[c * NB + t] = (float)tab / 255.0f;
        }
    }
    __syncthreads();

    // --- dense out3 + loss streaming pass (exactly one 4-pixel group/thread) ---
    const int n4 = HH / 4;
    const int k = blockIdx.x * 256 + t;
    uint4 pk = pkv[k];                       // bins bytes 0-2, mark bit 24
    float s = 0.0f;
#pragma unroll
    for (int c = 0; c < 3; ++c) {
        const float* tc = &tl[c * NB];
        int sh = 8 * c;
        float4 a = out1v[c * n4 + k];
        float4 b = out2v[c * n4 + k];
        float4 o;
        o.x = (pk.x & MARK) ? tc[(pk.x >> sh) & 255u] : a.x;
        o.y = (pk.y & MARK) ? tc[(pk.y >> sh) & 255u] : a.y;
        o.z = (pk.z & MARK) ? tc[(pk.z >> sh) & 255u] : a.z;
        o.w = (pk.w & MARK) ? tc[(pk.w >> sh) & 255u] : a.w;
        out3v[c * n4 + k] = o;
        s += fabsf(b.x - o.x) + fabsf(b.y - o.y) + fabsf(b.z - o.z) + fabsf(b.w - o.w);
    }
#pragma unroll
    for (int off = 32; off > 0; off >>= 1) s += __shfl_down(s, off);
    if (lane == 0) ws[wave] = s;
    __syncthreads();
    if (t == 0) {
        float tsum = ws[0] + ws[1] + ws[2] + ws[3];
        atomicAdd(loss, tsum * (1.0f / (float)CHW));
    }
}

extern "C" void kernel_launch(void* const* d_in, const int* in_sizes, int n_in,
                              void* d_out, int out_size, void* d_ws, size_t ws_size,
                              hipStream_t stream)
{
    const float* inp  = (const float*)d_in[0];
    const float* tar  = (const float*)d_in[1];
    const float* rfp  = (const float*)d_in[2];
    const float* msrc = (const float*)d_in[3];
    const float* mtar = (const float*)d_in[4];
    // d_in[5] = target_data_eye (unused by the reference computation)
    const int* i0 = (const int*)d_in[6];
    const int* i1 = (const int*)d_in[7];
    const int* i2 = (const int*)d_in[8];
    const int* i3 = (const int*)d_in[9];
    int n = in_sizes[6];

    float* out0 = (float*)d_out;
    float* out1 = out0 + CHW;
    float* out2 = out1 + CHW;
    float* out3 = out2 + CHW;
    float* loss = out3 + CHW;

    // workspace layout
    unsigned int* ghist  = (unsigned int*)d_ws;                      // [0, 6144): 1536 u32
    unsigned int* pk_dst = (unsigned int*)((char*)d_ws + 8192);      // HH u32 (4 MB)
    unsigned int* pk_ref = pk_dst + HH;                              // HH u32 (4 MB)

    k_elementwise<<<HH / 4 / 256, 256, 0, stream>>>(
        (const float4*)inp, (const float4*)tar, (const float4*)rfp,
        (const float4*)msrc, (const float4*)mtar,
        (float4*)out0, (float4*)out1, (float4*)out2,
        (uint4*)pk_dst, (uint4*)pk_ref, ghist, loss);

    k_hist<<<HIST_BLOCKS, HIST_THREADS, 0, stream>>>(pk_dst, pk_ref, i0, i1, i2, i3, ghist, n);

    k_finalize<<<FIN_BLOCKS, 256, 0, stream>>>(
        (const uint4*)ghist, (const uint4*)pk_dst,
        (const float4*)out1, (const float4*)out2, (float4*)out3, loss);
}